// Round 10
// baseline (113.142 us; speedup 1.0000x reference)
//
#include <hip/hip_runtime.h>

#define D_DIM 512

typedef float f32x2 __attribute__((ext_vector_type(2)));

__device__ __forceinline__ float flog2(float x) {
    return __builtin_amdgcn_logf(x);   // v_log_f32 (= log2); inputs >= ~4e-6, no denormal wrapper
}

// ============ fused single-kernel JSD ============
// out[i,j] = 1 + 0.5*(Ea[i]+Eb[j]) - 0.5*sum_d t*log2(t), t = a_i[d]+b_j[d]
//
// Round-9 main structure (57.6 us, at the serial-issue floor: busy ~= logs 27us
// + pk ops 7us + overhead 6us) + FUSED entropy prologue. The separate entropy
// kernel + E round-trip cost ~half the 49us fixed overhead; each block instead
// redundantly computes Ea for its 32 rows and Eb for its 32 cols (128 log+fma
// per thread ~ 0.55us, L2-fed), stashed in LDS, read at epilogue. The prologue
// also hides chunk-0 staging latency. One launch total.
// Closed levers (do not revisit): >4 waves/SIMD (R5 spill @64-cap, 845 MB
// scratch), sched_barrier region pinning (R7 spill), inline-asm ds_read
// pipeline (R8 regalloc race -> NaN), compiler-visible 2-set pipelining (R6:
// scheduler sinks loads, VGPR stays 52).
constexpr int DK  = 16;          // d per chunk (row = 64 B in LDS, 4 float4 slots)
constexpr int QD  = 128;         // d per wave (quarter)
constexpr int NCH = QD / DK;     // 8

#define GLDS(gp, lp)                                                           \
    __builtin_amdgcn_global_load_lds(                                          \
        (const __attribute__((address_space(1))) void*)(gp),                   \
        (__attribute__((address_space(3))) void*)(lp), 16, 0, 0)

__global__ __launch_bounds__(256, 4)
void jsd_main_kernel(const float* __restrict__ a, const float* __restrict__ b,
                     float* __restrict__ out, int N, int M) {
    __shared__ __align__(16) float lds[4][2][2][32][DK];   // [wave][buf][A/B][row][d] = 32 KB
    __shared__ __align__(16) float esh[64];                // [0..32) Ea local, [32..64) Eb local

    const int tid = threadIdx.x;
    const int w   = tid >> 6;        // wave = d-quarter
    const int l   = tid & 63;
    const int lr  = l >> 3;          // lane row group: rows 4*lr..4*lr+3
    const int lc  = l & 7;           // lane col group: cols 4*lc..4*lc+3
    const int rowBase = blockIdx.y * 32;
    const int colBase = blockIdx.x * 32;

    // Hoisted per-lane swizzled staging source. Lane l stages (row srow, slot
    // (l&3)^((srow>>2)&3)) of each 16-row half; swizzle value == (l>>4)&3 for
    // BOTH halves. Advance by DK floats per chunk.
    const int srow = l >> 2;                            // 0..15
    const int scol = 4 * ((l & 3) ^ ((l >> 4) & 3));    // swizzled 16B slot
    const float* gA = a + (size_t)(rowBase + srow) * D_DIM + w * QD + scol;
    const float* gB = b + (size_t)(colBase + srow) * D_DIM + w * QD + scol;

    float* A0 = &lds[w][0][0][0][0];
    float* B0 = &lds[w][0][1][0][0];
    float* A1 = &lds[w][1][0][0][0];
    float* B1 = &lds[w][1][1][0][0];

    f32x2 acc2[4][4];
#pragma unroll
    for (int i = 0; i < 4; ++i)
#pragma unroll
        for (int j = 0; j < 4; ++j) acc2[i][j] = (f32x2){0.f, 0.f};

    // issue chunk-0 staging first; the entropy prologue hides its latency
    GLDS(gA, A0); GLDS(gA + 16 * D_DIM, A0 + 16 * DK);
    GLDS(gB, B0); GLDS(gB + 16 * D_DIM, B0 + 16 * DK);

    // -------- fused entropy prologue --------
    // 64 logical rows (32 a-rows then 32 b-cols); wave w owns rows w*16..+15.
    // lane l: row w*16+(l&15), d-quarter l>>4 (32 float4s); xor-reduce over
    // the 4 quarter-lanes; lanes 0..15 write esh. L2-fed, ~0.55us/wave.
    {
        const int rl = l & 15;
        const float* esrc = (w < 2) ? (a + (size_t)(rowBase + w * 16 + rl) * D_DIM)
                                    : (b + (size_t)(colBase + (w - 2) * 16 + rl) * D_DIM);
        const float4* e4 = (const float4*)esrc + (l >> 4) * 32;
        float es = 0.f;
#pragma unroll 8
        for (int k = 0; k < 32; ++k) {
            float4 v = e4[k];
            es = fmaf(v.x, flog2(v.x), es);
            es = fmaf(v.y, flog2(v.y), es);
            es = fmaf(v.z, flog2(v.z), es);
            es = fmaf(v.w, flog2(v.w), es);
        }
        es += __shfl_xor(es, 16, 64);
        es += __shfl_xor(es, 32, 64);
        if (l < 16) esh[w * 16 + rl] = es;
        // read at epilogue, ordered by the merge __syncthreads below
    }

#define LOADQ(qc, BUFA, BUFB, AV, BV)                                          \
    do {                                                                       \
        const int sa_ = (((qc) ^ lr) & 3) << 2;                                \
        const int sb_ = (((qc) ^ lc) & 3) << 2;                                \
        _Pragma("unroll") for (int i_ = 0; i_ < 4; ++i_) {                     \
            AV[i_] = *(const float4*)&BUFA[(4 * lr + i_) * DK + sa_];          \
            BV[i_] = *(const float4*)&BUFB[(4 * lc + i_) * DK + sb_];          \
        }                                                                      \
    } while (0)

#define COMPQ(AV, BV)                                                          \
    do {                                                                       \
        _Pragma("unroll") for (int rr_ = 0; rr_ < 4; ++rr_) {                  \
            const f32x2 a0_ = {AV[rr_].x, AV[rr_].y};                          \
            const f32x2 a1_ = {AV[rr_].z, AV[rr_].w};                          \
            _Pragma("unroll") for (int cc_ = 0; cc_ < 4; ++cc_) {              \
                f32x2 t0_ = a0_ + (f32x2){BV[cc_].x, BV[cc_].y};               \
                f32x2 t1_ = a1_ + (f32x2){BV[cc_].z, BV[cc_].w};               \
                f32x2 l0_ = {flog2(t0_.x), flog2(t0_.y)};                      \
                f32x2 l1_ = {flog2(t1_.x), flog2(t1_.y)};                      \
                acc2[rr_][cc_] = __builtin_elementwise_fma(t0_, l0_, acc2[rr_][cc_]); \
                acc2[rr_][cc_] = __builtin_elementwise_fma(t1_, l1_, acc2[rr_][cc_]); \
            }                                                                  \
        }                                                                      \
    } while (0)

// software-pipelined q loop (round-6 shape; compiler-scheduled)
#define CHUNK(AW, BW)                                                          \
    do {                                                                       \
        LOADQ(0, AW, BW, avA, bvA);                                            \
        LOADQ(1, AW, BW, avB, bvB);                                            \
        COMPQ(avA, bvA);                                                       \
        LOADQ(2, AW, BW, avA, bvA);                                            \
        COMPQ(avB, bvB);                                                       \
        LOADQ(3, AW, BW, avB, bvB);                                            \
        COMPQ(avA, bvA);                                                       \
        COMPQ(avB, bvB);                                                       \
    } while (0)

#define WAITSTAGE() asm volatile("s_waitcnt vmcnt(0)" ::: "memory")

    float4 avA[4], bvA[4], avB[4], bvB[4];

#pragma unroll 1
    for (int ck = 0; ck < NCH - 2; ck += 2) {
        WAITSTAGE();                                   // buf0 chunk landed
        gA += DK; gB += DK;
        GLDS(gA, A1); GLDS(gA + 16 * D_DIM, A1 + 16 * DK);   // prefetch -> buf1
        GLDS(gB, B1); GLDS(gB + 16 * D_DIM, B1 + 16 * DK);
        __builtin_amdgcn_sched_barrier(0);             // keep load-issue ahead of compute
        CHUNK(A0, B0);

        WAITSTAGE();                                   // buf1 chunk landed
        gA += DK; gB += DK;
        GLDS(gA, A0); GLDS(gA + 16 * D_DIM, A0 + 16 * DK);   // prefetch -> buf0
        GLDS(gB, B0); GLDS(gB + 16 * D_DIM, B0 + 16 * DK);
        __builtin_amdgcn_sched_barrier(0);
        CHUNK(A1, B1);
    }
    // peeled tail: chunk NCH-2 (prefetch last), chunk NCH-1 (no prefetch)
    WAITSTAGE();
    gA += DK; gB += DK;
    GLDS(gA, A1); GLDS(gA + 16 * D_DIM, A1 + 16 * DK);
    GLDS(gB, B1); GLDS(gB + 16 * D_DIM, B1 + 16 * DK);
    __builtin_amdgcn_sched_barrier(0);
    CHUNK(A0, B0);
    WAITSTAGE();
    CHUNK(A1, B1);

#undef CHUNK
#undef COMPQ
#undef LOADQ
#undef WAITSTAGE

    // -------- 4-way d-merge via LDS (two barriers, no atomics) --------
    float accs[16];
#pragma unroll
    for (int i = 0; i < 16; ++i) accs[i] = acc2[i >> 2][i & 3].x + acc2[i >> 2][i & 3].y;

    __syncthreads();                       // everyone done reading their LDS slice (+ esh written)
    float* scratch = &lds[0][0][0][0][0];  // 8192 floats; need 4*16*65 = 4160 (esh is separate)
#pragma unroll
    for (int i = 0; i < 16; ++i)
        scratch[(w * 16 + i) * 65 + l] = accs[i];   // stride 65: conflict-free
    __syncthreads();

    // wave w combines + stores output rows 4*lr + w
    const int rr = w;
    float s[4];
#pragma unroll
    for (int cc = 0; cc < 4; ++cc) {
        float v = scratch[(0 * 16 + rr * 4 + cc) * 65 + l];
        v += scratch[(1 * 16 + rr * 4 + cc) * 65 + l];
        v += scratch[(2 * 16 + rr * 4 + cc) * 65 + l];
        v += scratch[(3 * 16 + rr * 4 + cc) * 65 + l];
        s[cc] = v;
    }
    const int row = rowBase + 4 * lr + rr;
    const float eav = esh[4 * lr + rr];
    const float4 eb = *(const float4*)&esh[32 + 4 * lc];
    const float base_v = 1.0f + 0.5f * eav;
    float4 v;
    v.x = fmaf(-0.5f, s[0], base_v + 0.5f * eb.x);
    v.y = fmaf(-0.5f, s[1], base_v + 0.5f * eb.y);
    v.z = fmaf(-0.5f, s[2], base_v + 0.5f * eb.z);
    v.w = fmaf(-0.5f, s[3], base_v + 0.5f * eb.w);
    *(float4*)(out + (size_t)row * M + colBase + 4 * lc) = v;
}

extern "C" void kernel_launch(void* const* d_in, const int* in_sizes, int n_in,
                              void* d_out, int out_size, void* d_ws, size_t ws_size,
                              hipStream_t stream) {
    const float* a = (const float*)d_in[0];
    const float* b = (const float*)d_in[1];
    const int N = in_sizes[0] / D_DIM;   // 1024
    const int M = in_sizes[1] / D_DIM;   // 1024

    dim3 grid(M / 32, N / 32);           // 32 x 32 = 1024 blocks -> 4 blocks/CU
    jsd_main_kernel<<<grid, 256, 0, stream>>>(a, b, (float*)d_out, N, M);
}

// Round 11
// 104.982 us; speedup vs baseline: 1.0777x; 1.0777x over previous
//
#include <hip/hip_runtime.h>

#define D_DIM 512

typedef float f32x2 __attribute__((ext_vector_type(2)));

__device__ __forceinline__ float flog2(float x) {
    return __builtin_amdgcn_logf(x);   // v_log_f32 (= log2); inputs >= ~4e-6, no denormal wrapper
}

// ============ per-row sums: E[row] = sum_d x*log2(x). One wave/row, 4 rows/block ============
__global__ __launch_bounds__(256)
void jsd_entropy_kernel(const float* __restrict__ a,
                        const float* __restrict__ b,
                        float* __restrict__ E, int N, int M) {
    const int wave = threadIdx.x >> 6;
    const int lane = threadIdx.x & 63;
    const int row = blockIdx.x * 4 + wave;
    if (row >= N + M) return;
    const float* src = (row < N) ? (a + (size_t)row * D_DIM)
                                 : (b + (size_t)(row - N) * D_DIM);
    const float4* s4 = (const float4*)src;
    float4 v0 = s4[lane];
    float4 v1 = s4[lane + 64];
    float s = 0.f;
    s = fmaf(v0.x, flog2(v0.x), s);
    s = fmaf(v0.y, flog2(v0.y), s);
    s = fmaf(v0.z, flog2(v0.z), s);
    s = fmaf(v0.w, flog2(v0.w), s);
    s = fmaf(v1.x, flog2(v1.x), s);
    s = fmaf(v1.y, flog2(v1.y), s);
    s = fmaf(v1.z, flog2(v1.z), s);
    s = fmaf(v1.w, flog2(v1.w), s);
#pragma unroll
    for (int off = 32; off > 0; off >>= 1) s += __shfl_down(s, off, 64);
    if (lane == 0) E[row] = s;
}

// ============ main ============
// out[i,j] = 1 + 0.5*(Ea[i]+Eb[j]) - 0.5*sum_d t*log2(t), t = a_i[d]+b_j[d]
//
// R9 skeleton, re-tiled for occupancy: 32x16 tile, 4x2 per lane, 4 waves =
// 4 INDEPENDENT d-quarters, no barrier in the main loop. Grid 2048 blocks;
// LDS 24 KB/block -> 6 blocks/CU = 6 independent waves/SIMD (R9 was
// grid-limited to 4). Per-lane state shrinks (acc 16 + 2 load sets 48 regs)
// so no VGPR cliff. LDS traffic 0.75 float/op ~= 31 us/CU < 41 us VALU floor.
// Closed levers (do not revisit): fusion of entropy (R10: +10us kernel, only
// -4us overhead), >registers-allow waves via launch_bounds cap (R5 spill),
// sched_barrier region pinning (R7 spill), asm ds_read pipeline (R8 NaN).
constexpr int TR  = 32;          // A-rows per block
constexpr int TC  = 16;          // B-cols per block
constexpr int DK  = 16;          // d per chunk (row = 64 B in LDS, 4 float4 slots)
constexpr int QD  = 128;         // d per wave (quarter)
constexpr int NCH = QD / DK;     // 8

#define GLDS(gp, lp)                                                           \
    __builtin_amdgcn_global_load_lds(                                          \
        (const __attribute__((address_space(1))) void*)(gp),                   \
        (__attribute__((address_space(3))) void*)(lp), 16, 0, 0)

__global__ __launch_bounds__(256, 4)
void jsd_main_kernel(const float* __restrict__ a, const float* __restrict__ b,
                     const float* __restrict__ Ea, const float* __restrict__ Eb,
                     float* __restrict__ out, int N, int M) {
    // per wave-buf: A = 32x16 floats @0, B = 16x16 floats @512 -> 768 floats
    __shared__ __align__(16) float lds[4][2][768];   // 24 KB

    const int tid = threadIdx.x;
    const int w   = tid >> 6;        // wave = d-quarter
    const int l   = tid & 63;
    const int lr  = l >> 3;          // lane row group (0..7): rows 4*lr..4*lr+3
    const int lc  = l & 7;           // lane col group (0..7): cols 2*lc..2*lc+1
    const int rowBase = blockIdx.y * TR;
    const int colBase = blockIdx.x * TC;

    // Hoisted per-lane swizzled staging source (same scheme as R9: LDS dest
    // linear, source slot = (l&3) ^ ((row>>2)&3); swizzle value == (l>>4)&3
    // for both 16-row halves). Advance by DK floats per chunk.
    const int srow = l >> 2;                            // 0..15
    const int scol = 4 * ((l & 3) ^ ((l >> 4) & 3));    // swizzled 16B slot
    const float* gA = a + (size_t)(rowBase + srow) * D_DIM + w * QD + scol;
    const float* gB = b + (size_t)(colBase + srow) * D_DIM + w * QD + scol;

    float* A0 = &lds[w][0][0];
    float* B0 = A0 + 512;
    float* A1 = &lds[w][1][0];
    float* B1 = A1 + 512;

    f32x2 acc2[4][2];
#pragma unroll
    for (int i = 0; i < 4; ++i)
#pragma unroll
        for (int j = 0; j < 2; ++j) acc2[i][j] = (f32x2){0.f, 0.f};

    // chunk 0: A rows 0-15, rows 16-31, B rows 0-15 (one GLDS each)
    GLDS(gA, A0); GLDS(gA + 16 * D_DIM, A0 + 256); GLDS(gB, B0);

#define LOADQ(qc, BUFA, BUFB, AV, BV)                                          \
    do {                                                                       \
        const int sa_ = (((qc) ^ lr) & 3) << 2;                                \
        const int sb_ = (((qc) ^ (lc >> 1)) & 3) << 2;                         \
        _Pragma("unroll") for (int i_ = 0; i_ < 4; ++i_)                       \
            AV[i_] = *(const float4*)&BUFA[(4 * lr + i_) * DK + sa_];          \
        _Pragma("unroll") for (int c_ = 0; c_ < 2; ++c_)                       \
            BV[c_] = *(const float4*)&BUFB[(2 * lc + c_) * DK + sb_];          \
    } while (0)

#define COMPQ(AV, BV)                                                          \
    do {                                                                       \
        _Pragma("unroll") for (int rr_ = 0; rr_ < 4; ++rr_) {                  \
            const f32x2 a0_ = {AV[rr_].x, AV[rr_].y};                          \
            const f32x2 a1_ = {AV[rr_].z, AV[rr_].w};                          \
            _Pragma("unroll") for (int cc_ = 0; cc_ < 2; ++cc_) {              \
                f32x2 t0_ = a0_ + (f32x2){BV[cc_].x, BV[cc_].y};               \
                f32x2 t1_ = a1_ + (f32x2){BV[cc_].z, BV[cc_].w};               \
                f32x2 l0_ = {flog2(t0_.x), flog2(t0_.y)};                      \
                f32x2 l1_ = {flog2(t1_.x), flog2(t1_.y)};                      \
                acc2[rr_][cc_] = __builtin_elementwise_fma(t0_, l0_, acc2[rr_][cc_]); \
                acc2[rr_][cc_] = __builtin_elementwise_fma(t1_, l1_, acc2[rr_][cc_]); \
            }                                                                  \
        }                                                                      \
    } while (0)

// software-pipelined q loop (R6/R9 shape; compiler-scheduled)
#define CHUNK(AW, BW)                                                          \
    do {                                                                       \
        LOADQ(0, AW, BW, avA, bvA);                                            \
        LOADQ(1, AW, BW, avB, bvB);                                            \
        COMPQ(avA, bvA);                                                       \
        LOADQ(2, AW, BW, avA, bvA);                                            \
        COMPQ(avB, bvB);                                                       \
        LOADQ(3, AW, BW, avB, bvB);                                            \
        COMPQ(avA, bvA);                                                       \
        COMPQ(avB, bvB);                                                       \
    } while (0)

#define WAITSTAGE() asm volatile("s_waitcnt vmcnt(0)" ::: "memory")

    float4 avA[4], bvA[2], avB[4], bvB[2];

#pragma unroll 1
    for (int ck = 0; ck < NCH - 2; ck += 2) {
        WAITSTAGE();                                   // buf0 chunk landed
        gA += DK; gB += DK;
        GLDS(gA, A1); GLDS(gA + 16 * D_DIM, A1 + 256); GLDS(gB, B1);  // -> buf1
        __builtin_amdgcn_sched_barrier(0);             // keep load-issue ahead of compute
        CHUNK(A0, B0);

        WAITSTAGE();                                   // buf1 chunk landed
        gA += DK; gB += DK;
        GLDS(gA, A0); GLDS(gA + 16 * D_DIM, A0 + 256); GLDS(gB, B0);  // -> buf0
        __builtin_amdgcn_sched_barrier(0);
        CHUNK(A1, B1);
    }
    // peeled tail
    WAITSTAGE();
    gA += DK; gB += DK;
    GLDS(gA, A1); GLDS(gA + 16 * D_DIM, A1 + 256); GLDS(gB, B1);
    __builtin_amdgcn_sched_barrier(0);
    CHUNK(A0, B0);
    WAITSTAGE();
    CHUNK(A1, B1);

#undef CHUNK
#undef COMPQ
#undef LOADQ
#undef WAITSTAGE

    // -------- 4-way d-merge via LDS (two barriers, no atomics) --------
    float accs[8];
#pragma unroll
    for (int i = 0; i < 8; ++i) accs[i] = acc2[i >> 1][i & 1].x + acc2[i >> 1][i & 1].y;

    __syncthreads();                   // everyone done reading their LDS slice
    float* scratch = &lds[0][0][0];    // 6144 floats; need 4*8*65 = 2080
#pragma unroll
    for (int i = 0; i < 8; ++i)
        scratch[(w * 8 + i) * 65 + l] = accs[i];   // stride 65: conflict-free
    __syncthreads();

    // thread (w,l) combines + stores (row 4*lr+w, cols 2*lc..2*lc+1)
    float s0 = 0.f, s1 = 0.f;
#pragma unroll
    for (int w2 = 0; w2 < 4; ++w2) {
        s0 += scratch[(w2 * 8 + 2 * w + 0) * 65 + l];
        s1 += scratch[(w2 * 8 + 2 * w + 1) * 65 + l];
    }
    const int row = rowBase + 4 * lr + w;
    const int col = colBase + 2 * lc;
    const float eav = Ea[row];
    const float2 eb = *(const float2*)&Eb[col];
    const float base_v = 1.0f + 0.5f * eav;
    float2 v;
    v.x = fmaf(-0.5f, s0, base_v + 0.5f * eb.x);
    v.y = fmaf(-0.5f, s1, base_v + 0.5f * eb.y);
    *(float2*)(out + (size_t)row * M + col) = v;
}

extern "C" void kernel_launch(void* const* d_in, const int* in_sizes, int n_in,
                              void* d_out, int out_size, void* d_ws, size_t ws_size,
                              hipStream_t stream) {
    const float* a = (const float*)d_in[0];
    const float* b = (const float*)d_in[1];
    const int N = in_sizes[0] / D_DIM;   // 1024
    const int M = in_sizes[1] / D_DIM;   // 1024
    float* E = (float*)d_ws;             // Ea[0..N), Eb[N..N+M)

    jsd_entropy_kernel<<<(N + M + 3) / 4, 256, 0, stream>>>(a, b, E, N, M);

    dim3 grid(M / TC, N / TR);           // 64 x 32 = 2048 blocks -> 6 blocks/CU (LDS-limited)
    jsd_main_kernel<<<grid, 256, 0, stream>>>(a, b, E, E + N, (float*)d_out, N, M);
}